// Round 15
// baseline (65.514 us; speedup 1.0000x reference)
//
#include <hip/hip_runtime.h>
#include <math.h>

// ContactModel R15: R14 (jori LDS read-staging + LDS-coalesced big stores)
// + TIME-MULTIPLEXED joints staging through the SAME 38KB LDS buffer.
// Phase A: stage touched joints floats (12/row x 257 rows, stride-13 pad)
//          coalesced; threads pull own+prev joints into 24 registers; barrier.
// Phase B: R14's jori staging (stride-37) + compute, verbatim.
// Eliminates the last ~2000 scattered-read line-accesses/block (joints own+
// prev at 288B lane stride). 4 blocks/CU preserved (38KB LDS, VGPR ~108).
// Arithmetic bitwise-identical to R14 (59.8 us, absmax 524288).

__device__ __constant__ float c_local[12][3] = {
    {0.00190115788407966f, -0.01f, -0.00382630379623308f},
    {0.148386399942063f,   -0.01f, -0.028713422052654f},
    {0.133001170607051f,   -0.01f,  0.0516362473449566f},
    {0.0662346661991635f,  -0.01f,  0.0263641606741698f},
    {0.06f,                -0.01f, -0.0187603084619177f},
    {0.045f,               -0.01f,  0.0618569567549652f},
    {0.00190115788407966f, -0.01f,  0.00382630379623308f},
    {0.148386399942063f,   -0.01f,  0.028713422052654f},
    {0.133001170607051f,   -0.01f, -0.0516362473449566f},
    {0.0662346661991635f,  -0.01f, -0.0263641606741698f},
    {0.06f,                -0.01f,  0.0187603084619177f},
    {0.045f,               -0.01f, -0.0618569567549652f}};

__global__ __launch_bounds__(256)
void contact_kernel(const float* __restrict__ joints,
                    const float* __restrict__ jori,
                    float* __restrict__ out, const int B)
{
    __shared__ float sbuf[257 * 37];          // 38036 B; 4 blocks/CU = 152 KB
    const int tid = threadIdx.x;
    const int b = blockIdx.x * blockDim.x + tid;
    const bool full = ((B & 255) == 0);       // block-uniform: barriers safe

    float px[12], py[12], pz[12];
    float fx[12], fy[12], fz[12];             // velocity first, then force

    if (full) {
        const long B0 = (long)blockIdx.x * 256;

        // ---- PHASE A: joints staging (stride-13 rows; 13 coprime 32) ----
        // row r = batch B0-1+r (clamped at 0); col c: c<6 -> joints float
        // 12+c (bodies 4,5 pos), c>=6 -> 21+c (= 27+(c-6), bodies 9,10 pos).
        for (int idx = tid; idx < 257 * 12; idx += 256) {
            const int r = idx / 12, c = idx - r * 12;
            long br = B0 - 1 + r;
            br = br < 0 ? 0 : br;
            const int off = (c < 6) ? (12 + c) : (21 + c);
            sbuf[r * 13 + c] = joints[br * 72 + off];
        }
        __syncthreads();
        float J[12], P[12];
        #pragma unroll
        for (int c = 0; c < 12; ++c) {
            J[c] = sbuf[(tid + 1) * 13 + c];   // own row
            P[c] = sbuf[tid * 13 + c];         // prev row
        }
        __syncthreads();

        // ---- PHASE B: jori staging (R14 verbatim) ----
        for (int idx = tid; idx < 257 * 36; idx += 256) {
            const int r = idx / 36, c = idx - r * 36;
            long br = B0 - 1 + r;
            br = br < 0 ? 0 : br;
            const int off = (c < 18) ? (36 + c) : (63 + c);
            sbuf[r * 37 + c] = jori[br * 216 + off];
        }
        __syncthreads();

        const float* own = &sbuf[(tid + 1) * 37];
        const float* prv = &sbuf[tid * 37];
        const int sbeg[4] = {0, 4, 6, 10};
        const int scnt[4] = {4, 2, 4, 2};
        #pragma unroll
        for (int bi = 0; bi < 4; ++bi) {
            const float jx = J[bi*3+0], jy = J[bi*3+1], jz = J[bi*3+2];
            const float kx = P[bi*3+0], ky = P[bi*3+1], kz = P[bi*3+2];
            const float* m  = own + bi*9;
            const float m00=m[0],m01=m[1],m02=m[2];
            const float m10=m[3],m11=m[4],m12=m[5];
            const float m20=m[6],m21=m[7],m22=m[8];
            const float* nn = prv + bi*9;
            const float n00=nn[0],n01=nn[1],n02=nn[2];
            const float n10=nn[3],n11=nn[4],n12=nn[5];
            const float n20=nn[6],n21=nn[7],n22=nn[8];
            #pragma unroll
            for (int si = 0; si < 4; ++si) {
                if (si < scnt[bi]) {
                    const int s = sbeg[bi] + si;
                    const float lx = c_local[s][0];
                    const float ly = c_local[s][1];
                    const float lz = c_local[s][2];
                    const float ax = jx + m00*lx + m01*ly + m02*lz;
                    const float ay = jy + m10*lx + m11*ly + m12*lz;
                    const float az = jz + m20*lx + m21*ly + m22*lz;
                    const float bx = kx + n00*lx + n01*ly + n02*lz;
                    const float by = ky + n10*lx + n11*ly + n12*lz;
                    const float bz = kz + n20*lx + n21*ly + n22*lz;
                    px[s] = ax; py[s] = ay; pz[s] = az;
                    fx[s] = (ax - bx) * 20.0f;   // 1/DT = 20
                    fy[s] = (ay - by) * 20.0f;
                    fz[s] = (az - bz) * 20.0f;
                }
            }
        }
    } else {
        if (b >= B) return;
        const int bp = (b > 0) ? (b - 1) : b;
        const float* jr  = joints + (size_t)b  * 72;
        const float* jrp = joints + (size_t)bp * 72;
        const float* mr  = jori + (size_t)b  * 216;
        const float* mrp = jori + (size_t)bp * 216;
        const int bodies[4] = {4, 5, 9, 10};
        const int sbeg[4]   = {0, 4, 6, 10};
        const int scnt[4]   = {4, 2, 4, 2};
        #pragma unroll
        for (int bi = 0; bi < 4; ++bi) {
            const int body = bodies[bi];
            const float jx = jr[body*3+0], jy = jr[body*3+1], jz = jr[body*3+2];
            const float kx = jrp[body*3+0], ky = jrp[body*3+1], kz = jrp[body*3+2];
            const float* m = mr + body*9;
            const float m00=m[0],m01=m[1],m02=m[2];
            const float m10=m[3],m11=m[4],m12=m[5];
            const float m20=m[6],m21=m[7],m22=m[8];
            const float* nn = mrp + body*9;
            const float n00=nn[0],n01=nn[1],n02=nn[2];
            const float n10=nn[3],n11=nn[4],n12=nn[5];
            const float n20=nn[6],n21=nn[7],n22=nn[8];
            #pragma unroll
            for (int si = 0; si < 4; ++si) {
                if (si < scnt[bi]) {
                    const int s = sbeg[bi] + si;
                    const float lx = c_local[s][0];
                    const float ly = c_local[s][1];
                    const float lz = c_local[s][2];
                    const float ax = jx + m00*lx + m01*ly + m02*lz;
                    const float ay = jy + m10*lx + m11*ly + m12*lz;
                    const float az = jz + m20*lx + m21*ly + m22*lz;
                    const float bx = kx + n00*lx + n01*ly + n02*lz;
                    const float by = ky + n10*lx + n11*ly + n12*lz;
                    const float bz = kz + n20*lx + n21*ly + n22*lz;
                    px[s] = ax; py[s] = ay; pz[s] = az;
                    fx[s] = (ax - bx) * 20.0f;
                    fy[s] = (ay - by) * 20.0f;
                    fz[s] = (az - bz) * 20.0f;
                }
            }
        }
    }

    // ---- contact forces (champion numerics, in-place over velocity) ----
    const float KF  = 1077.21734501594f;                 // 0.5 * 100000**(2/3)
    const float CFH = (4.0f/3.0f) * KF * sqrtf(0.032f * KF);
    #pragma unroll
    for (int s = 0; s < 12; ++s) {
        const float vx = fx[s], vy = fy[s], vz = fz[s];
        const float ind     = -py[s];                    // GROUND_HEIGHT = 0
        const float ind_vel = -vy;
        const float q   = ind*ind + 1e-5f;
        const float fH  = CFH * sqrtf(q * sqrtf(q));     // q^0.75
        const float fHd = fH * (1.0f + 0.3f * ind_vel);  // 1.5*DISSIPATION = 0.3
        const float t1 = (0.5f*tanhf(50.0f*(ind_vel + 3.3333333333333335f)) + 0.5f) + 1e-16f;
        const float t2 = (0.5f*tanhf(300.0f*ind) + 0.5f) + 1e-16f;
        const float fn = t1 * t2 * fHd;
        const float vslip = sqrtf(vx*vx + vz*vz + 1e-5f);
        const float vrel  = vslip * 5.0f;                // / TRANSITION_VELOCITY
        // STATIC==DYNAMIC==0.8 -> 2*(S-D)/(1+vrel^2) term is exactly 0
        const float mu  = fminf(vrel, 1.0f) * 0.8f + 0.5f * vslip;
        const float ffr = fn * mu;
        const float sc  = ffr / (vslip + 1e-5f);
        fx[s] = -sc * vx;
        fy[s] = fn;
        fz[s] = -sc * vz;
    }

    // ---- group reductions (champion code) ----
    float res[3][9];
    const int gs0[3] = {0, 0, 6};
    const int gs1[3] = {12, 6, 12};
    #pragma unroll
    for (int g = 0; g < 3; ++g) {
        float Fx=0.f, Fy=0.f, Fz=0.f, tw=0.f, sx=0.f, sz=0.f;
        #pragma unroll
        for (int s = 0; s < 12; ++s) {
            if (s >= gs0[g] && s < gs1[g]) {
                Fx += fx[s]; Fy += fy[s]; Fz += fz[s];
                const float w = fy[s] > 0.f ? fy[s] : 0.f;
                tw += w;
                sx += px[s] * w;
                sz += pz[s] * w;
            }
        }
        const bool has = tw > 0.f;
        const float cx = has ? sx / tw : 0.f;
        const float cz = has ? sz / tw : 0.f;
        float Tx=0.f, Ty=0.f, Tz=0.f;
        #pragma unroll
        for (int s = 0; s < 12; ++s) {
            if (s >= gs0[g] && s < gs1[g]) {
                if (fy[s] > 0.f) {
                    const float rx = px[s]-cx, ry = py[s], rz = pz[s]-cz;  // cy==0
                    Tx += ry*fz[s] - rz*fy[s];
                    Ty += rz*fx[s] - rx*fz[s];
                    Tz += rx*fy[s] - ry*fx[s];
                }
            }
        }
        res[g][0]=Fx; res[g][1]=Fy; res[g][2]=Fz;
        res[g][3]=Tx; res[g][4]=Ty; res[g][5]=Tz;
        res[g][6]=cx; res[g][7]=0.f; res[g][8]=cz;
    }

    // ---- small-region stores (scalar, R12 form) ----
    const size_t sB = (size_t)B;
    const size_t t3 = (size_t)b * 3;
    float* o;
    o = out;           o[t3]=res[0][0]; o[t3+1]=res[0][1]; o[t3+2]=res[0][2];
    o = out + sB*3;    o[t3]=res[0][3]; o[t3+1]=res[0][4]; o[t3+2]=res[0][5];
    o = out + sB*6;    o[t3]=res[0][6]; o[t3+1]=res[0][7]; o[t3+2]=res[0][8];
    o = out + sB*81;   o[t3]=res[1][0]; o[t3+1]=res[1][1]; o[t3+2]=res[1][2];
    o = out + sB*84;   o[t3]=res[2][0]; o[t3+1]=res[2][1]; o[t3+2]=res[2][2];
    o = out + sB*87;   o[t3]=res[1][3]; o[t3+1]=res[1][4]; o[t3+2]=res[1][5];
    o = out + sB*90;   o[t3]=res[2][3]; o[t3+1]=res[2][4]; o[t3+2]=res[2][5];
    o = out + sB*93;   o[t3]=res[1][6]; o[t3+1]=res[1][7]; o[t3+2]=res[1][8];
    o = out + sB*96;   o[t3]=res[2][6]; o[t3+1]=res[2][7]; o[t3+2]=res[2][8];

    // ---- big-array stores (R12/R14 verbatim) ----
    if (full) {
        __syncthreads();   // all LDS reads of staged jori complete
        #pragma unroll
        for (int s = 0; s < 12; ++s) {
            sbuf[tid*37 + s*3+0] = fx[s];
            sbuf[tid*37 + s*3+1] = fy[s];
            sbuf[tid*37 + s*3+2] = fz[s];
        }
        __syncthreads();
        {
            float4* dst = reinterpret_cast<float4*>(out + sB*9) + (size_t)blockIdx.x*2304;
            #pragma unroll
            for (int i = 0; i < 9; ++i) {
                const int j = tid + 256*i;
                const int g = 4*j;
                float v[4];
                #pragma unroll
                for (int e = 0; e < 4; ++e) {
                    const int gg = g+e; const int r = gg/36; const int c = gg-r*36;
                    v[e] = sbuf[r*37+c];
                }
                dst[j] = make_float4(v[0],v[1],v[2],v[3]);
            }
        }
        __syncthreads();
        #pragma unroll
        for (int s = 0; s < 12; ++s) {
            sbuf[tid*37 + s*3+0] = px[s];
            sbuf[tid*37 + s*3+1] = py[s];
            sbuf[tid*37 + s*3+2] = pz[s];
        }
        __syncthreads();
        {
            float4* dst = reinterpret_cast<float4*>(out + sB*45) + (size_t)blockIdx.x*2304;
            #pragma unroll
            for (int i = 0; i < 9; ++i) {
                const int j = tid + 256*i;
                const int g = 4*j;
                float v[4];
                #pragma unroll
                for (int e = 0; e < 4; ++e) {
                    const int gg = g+e; const int r = gg/36; const int c = gg-r*36;
                    v[e] = sbuf[r*37+c];
                }
                dst[j] = make_float4(v[0],v[1],v[2],v[3]);
            }
        }
    } else {
        float* osf = out + sB*9  + (size_t)b*36;
        float* opp = out + sB*45 + (size_t)b*36;
        #pragma unroll
        for (int s = 0; s < 12; ++s) {
            osf[s*3+0]=fx[s]; osf[s*3+1]=fy[s]; osf[s*3+2]=fz[s];
            opp[s*3+0]=px[s]; opp[s*3+1]=py[s]; opp[s*3+2]=pz[s];
        }
    }
}

extern "C" void kernel_launch(void* const* d_in, const int* in_sizes, int n_in,
                              void* d_out, int out_size, void* d_ws, size_t ws_size,
                              hipStream_t stream) {
    const float* joints = (const float*)d_in[0];
    const float* jori   = (const float*)d_in[1];
    float* out = (float*)d_out;
    const int B = in_sizes[0] / 72;   // joints is (B, 24, 3)
    const int block = 256;
    const int grid  = (B + block - 1) / block;
    contact_kernel<<<grid, block, 0, stream>>>(joints, jori, out, B);
}

// Round 16
// 59.249 us; speedup vs baseline: 1.1057x; 1.1057x over previous
//
#include <hip/hip_runtime.h>
#include <math.h>

// ContactModel R16 = R14 champion (revert of R15's joints-staging regression).
// Structure: direct joints loads (issue immediately, hide staging latency) +
// coalesced jori LDS read-staging (stride-37, 38KB, 4 blocks/CU preserved) +
// LDS-coalesced big-array stores (R12) + scalar small stores.
// History: R1 67.2 -> R12 63.5 (store coalescing) -> R14 59.8 (jori staging).
// R13 (small-store coalescing), R15 (joints time-multiplex) both regressed.

__device__ __constant__ float c_local[12][3] = {
    {0.00190115788407966f, -0.01f, -0.00382630379623308f},
    {0.148386399942063f,   -0.01f, -0.028713422052654f},
    {0.133001170607051f,   -0.01f,  0.0516362473449566f},
    {0.0662346661991635f,  -0.01f,  0.0263641606741698f},
    {0.06f,                -0.01f, -0.0187603084619177f},
    {0.045f,               -0.01f,  0.0618569567549652f},
    {0.00190115788407966f, -0.01f,  0.00382630379623308f},
    {0.148386399942063f,   -0.01f,  0.028713422052654f},
    {0.133001170607051f,   -0.01f, -0.0516362473449566f},
    {0.0662346661991635f,  -0.01f, -0.0263641606741698f},
    {0.06f,                -0.01f,  0.0187603084619177f},
    {0.045f,               -0.01f, -0.0618569567549652f}};

__global__ __launch_bounds__(256)
void contact_kernel(const float* __restrict__ joints,
                    const float* __restrict__ jori,
                    float* __restrict__ out, const int B)
{
    __shared__ float sbuf[257 * 37];          // 38036 B; 4 blocks/CU = 152 KB
    const int tid = threadIdx.x;
    const int b = blockIdx.x * blockDim.x + tid;
    const bool full = ((B & 255) == 0);       // block-uniform: barriers safe

    float px[12], py[12], pz[12];
    float fx[12], fy[12], fz[12];             // velocity first, then force

    const int bp = (b > 0) ? (b - 1) : b;     // bp==b => vel exactly 0 (ref)
    const float* jr  = joints + (size_t)b  * 72;
    const float* jrp = joints + (size_t)bp * 72;

    if (full) {
        // ---- coalesced jori staging: rows B0-1 .. B0+255 (clamped) ----
        // LDS row r, col c: c in [0,18) -> jori float 36+c (bodies 4,5 ori),
        //                   c in [18,36) -> jori float 63+c (bodies 9,10 ori).
        const long B0 = (long)blockIdx.x * 256;
        for (int idx = tid; idx < 257 * 36; idx += 256) {
            const int r = idx / 36, c = idx - r * 36;
            long br = B0 - 1 + r;
            br = br < 0 ? 0 : br;             // top clamp unneeded (full blocks)
            const int off = (c < 18) ? (36 + c) : (63 + c);
            sbuf[r * 37 + c] = jori[br * 216 + off];
        }
        __syncthreads();

        const float* own = &sbuf[(tid + 1) * 37];
        const float* prv = &sbuf[tid * 37];
        const int bodies[4] = {4, 5, 9, 10};
        const int sbeg[4]   = {0, 4, 6, 10};
        const int scnt[4]   = {4, 2, 4, 2};
        #pragma unroll
        for (int bi = 0; bi < 4; ++bi) {
            const int body = bodies[bi];
            const float jx = jr[body*3+0], jy = jr[body*3+1], jz = jr[body*3+2];
            const float kx = jrp[body*3+0], ky = jrp[body*3+1], kz = jrp[body*3+2];
            const float* m  = own + bi*9;
            const float m00=m[0],m01=m[1],m02=m[2];
            const float m10=m[3],m11=m[4],m12=m[5];
            const float m20=m[6],m21=m[7],m22=m[8];
            const float* nn = prv + bi*9;
            const float n00=nn[0],n01=nn[1],n02=nn[2];
            const float n10=nn[3],n11=nn[4],n12=nn[5];
            const float n20=nn[6],n21=nn[7],n22=nn[8];
            #pragma unroll
            for (int si = 0; si < 4; ++si) {
                if (si < scnt[bi]) {
                    const int s = sbeg[bi] + si;
                    const float lx = c_local[s][0];
                    const float ly = c_local[s][1];
                    const float lz = c_local[s][2];
                    const float ax = jx + m00*lx + m01*ly + m02*lz;
                    const float ay = jy + m10*lx + m11*ly + m12*lz;
                    const float az = jz + m20*lx + m21*ly + m22*lz;
                    const float bx = kx + n00*lx + n01*ly + n02*lz;
                    const float by = ky + n10*lx + n11*ly + n12*lz;
                    const float bz = kz + n20*lx + n21*ly + n22*lz;
                    px[s] = ax; py[s] = ay; pz[s] = az;
                    fx[s] = (ax - bx) * 20.0f;   // 1/DT = 20
                    fy[s] = (ay - by) * 20.0f;
                    fz[s] = (az - bz) * 20.0f;
                }
            }
        }
    } else {
        if (b >= B) return;
        const float* mr  = jori + (size_t)b  * 216;
        const float* mrp = jori + (size_t)bp * 216;
        const int bodies[4] = {4, 5, 9, 10};
        const int sbeg[4]   = {0, 4, 6, 10};
        const int scnt[4]   = {4, 2, 4, 2};
        #pragma unroll
        for (int bi = 0; bi < 4; ++bi) {
            const int body = bodies[bi];
            const float jx = jr[body*3+0], jy = jr[body*3+1], jz = jr[body*3+2];
            const float kx = jrp[body*3+0], ky = jrp[body*3+1], kz = jrp[body*3+2];
            const float* m = mr + body*9;
            const float m00=m[0],m01=m[1],m02=m[2];
            const float m10=m[3],m11=m[4],m12=m[5];
            const float m20=m[6],m21=m[7],m22=m[8];
            const float* nn = mrp + body*9;
            const float n00=nn[0],n01=nn[1],n02=nn[2];
            const float n10=nn[3],n11=nn[4],n12=nn[5];
            const float n20=nn[6],n21=nn[7],n22=nn[8];
            #pragma unroll
            for (int si = 0; si < 4; ++si) {
                if (si < scnt[bi]) {
                    const int s = sbeg[bi] + si;
                    const float lx = c_local[s][0];
                    const float ly = c_local[s][1];
                    const float lz = c_local[s][2];
                    const float ax = jx + m00*lx + m01*ly + m02*lz;
                    const float ay = jy + m10*lx + m11*ly + m12*lz;
                    const float az = jz + m20*lx + m21*ly + m22*lz;
                    const float bx = kx + n00*lx + n01*ly + n02*lz;
                    const float by = ky + n10*lx + n11*ly + n12*lz;
                    const float bz = kz + n20*lx + n21*ly + n22*lz;
                    px[s] = ax; py[s] = ay; pz[s] = az;
                    fx[s] = (ax - bx) * 20.0f;
                    fy[s] = (ay - by) * 20.0f;
                    fz[s] = (az - bz) * 20.0f;
                }
            }
        }
    }

    // ---- contact forces (champion numerics, in-place over velocity) ----
    const float KF  = 1077.21734501594f;                 // 0.5 * 100000**(2/3)
    const float CFH = (4.0f/3.0f) * KF * sqrtf(0.032f * KF);
    #pragma unroll
    for (int s = 0; s < 12; ++s) {
        const float vx = fx[s], vy = fy[s], vz = fz[s];
        const float ind     = -py[s];                    // GROUND_HEIGHT = 0
        const float ind_vel = -vy;
        const float q   = ind*ind + 1e-5f;
        const float fH  = CFH * sqrtf(q * sqrtf(q));     // q^0.75
        const float fHd = fH * (1.0f + 0.3f * ind_vel);  // 1.5*DISSIPATION = 0.3
        const float t1 = (0.5f*tanhf(50.0f*(ind_vel + 3.3333333333333335f)) + 0.5f) + 1e-16f;
        const float t2 = (0.5f*tanhf(300.0f*ind) + 0.5f) + 1e-16f;
        const float fn = t1 * t2 * fHd;
        const float vslip = sqrtf(vx*vx + vz*vz + 1e-5f);
        const float vrel  = vslip * 5.0f;                // / TRANSITION_VELOCITY
        // STATIC==DYNAMIC==0.8 -> 2*(S-D)/(1+vrel^2) term is exactly 0
        const float mu  = fminf(vrel, 1.0f) * 0.8f + 0.5f * vslip;
        const float ffr = fn * mu;
        const float sc  = ffr / (vslip + 1e-5f);
        fx[s] = -sc * vx;
        fy[s] = fn;
        fz[s] = -sc * vz;
    }

    // ---- group reductions (champion code) ----
    float res[3][9];
    const int gs0[3] = {0, 0, 6};
    const int gs1[3] = {12, 6, 12};
    #pragma unroll
    for (int g = 0; g < 3; ++g) {
        float Fx=0.f, Fy=0.f, Fz=0.f, tw=0.f, sx=0.f, sz=0.f;
        #pragma unroll
        for (int s = 0; s < 12; ++s) {
            if (s >= gs0[g] && s < gs1[g]) {
                Fx += fx[s]; Fy += fy[s]; Fz += fz[s];
                const float w = fy[s] > 0.f ? fy[s] : 0.f;
                tw += w;
                sx += px[s] * w;
                sz += pz[s] * w;
            }
        }
        const bool has = tw > 0.f;
        const float cx = has ? sx / tw : 0.f;
        const float cz = has ? sz / tw : 0.f;
        float Tx=0.f, Ty=0.f, Tz=0.f;
        #pragma unroll
        for (int s = 0; s < 12; ++s) {
            if (s >= gs0[g] && s < gs1[g]) {
                if (fy[s] > 0.f) {
                    const float rx = px[s]-cx, ry = py[s], rz = pz[s]-cz;  // cy==0
                    Tx += ry*fz[s] - rz*fy[s];
                    Ty += rz*fx[s] - rx*fz[s];
                    Tz += rx*fy[s] - ry*fx[s];
                }
            }
        }
        res[g][0]=Fx; res[g][1]=Fy; res[g][2]=Fz;
        res[g][3]=Tx; res[g][4]=Ty; res[g][5]=Tz;
        res[g][6]=cx; res[g][7]=0.f; res[g][8]=cz;
    }

    // ---- small-region stores (scalar, R12 form) ----
    const size_t sB = (size_t)B;
    const size_t t3 = (size_t)b * 3;
    float* o;
    o = out;           o[t3]=res[0][0]; o[t3+1]=res[0][1]; o[t3+2]=res[0][2];
    o = out + sB*3;    o[t3]=res[0][3]; o[t3+1]=res[0][4]; o[t3+2]=res[0][5];
    o = out + sB*6;    o[t3]=res[0][6]; o[t3+1]=res[0][7]; o[t3+2]=res[0][8];
    o = out + sB*81;   o[t3]=res[1][0]; o[t3+1]=res[1][1]; o[t3+2]=res[1][2];
    o = out + sB*84;   o[t3]=res[2][0]; o[t3+1]=res[2][1]; o[t3+2]=res[2][2];
    o = out + sB*87;   o[t3]=res[1][3]; o[t3+1]=res[1][4]; o[t3+2]=res[1][5];
    o = out + sB*90;   o[t3]=res[2][3]; o[t3+1]=res[2][4]; o[t3+2]=res[2][5];
    o = out + sB*93;   o[t3]=res[1][6]; o[t3+1]=res[1][7]; o[t3+2]=res[1][8];
    o = out + sB*96;   o[t3]=res[2][6]; o[t3+1]=res[2][7]; o[t3+2]=res[2][8];

    // ---- big-array stores ----
    if (full) {
        __syncthreads();   // all LDS reads of staged jori complete
        #pragma unroll
        for (int s = 0; s < 12; ++s) {
            sbuf[tid*37 + s*3+0] = fx[s];
            sbuf[tid*37 + s*3+1] = fy[s];
            sbuf[tid*37 + s*3+2] = fz[s];
        }
        __syncthreads();
        {
            float4* dst = reinterpret_cast<float4*>(out + sB*9) + (size_t)blockIdx.x*2304;
            #pragma unroll
            for (int i = 0; i < 9; ++i) {
                const int j = tid + 256*i;
                const int g = 4*j;
                float v[4];
                #pragma unroll
                for (int e = 0; e < 4; ++e) {
                    const int gg = g+e; const int r = gg/36; const int c = gg-r*36;
                    v[e] = sbuf[r*37+c];
                }
                dst[j] = make_float4(v[0],v[1],v[2],v[3]);
            }
        }
        __syncthreads();
        #pragma unroll
        for (int s = 0; s < 12; ++s) {
            sbuf[tid*37 + s*3+0] = px[s];
            sbuf[tid*37 + s*3+1] = py[s];
            sbuf[tid*37 + s*3+2] = pz[s];
        }
        __syncthreads();
        {
            float4* dst = reinterpret_cast<float4*>(out + sB*45) + (size_t)blockIdx.x*2304;
            #pragma unroll
            for (int i = 0; i < 9; ++i) {
                const int j = tid + 256*i;
                const int g = 4*j;
                float v[4];
                #pragma unroll
                for (int e = 0; e < 4; ++e) {
                    const int gg = g+e; const int r = gg/36; const int c = gg-r*36;
                    v[e] = sbuf[r*37+c];
                }
                dst[j] = make_float4(v[0],v[1],v[2],v[3]);
            }
        }
    } else {
        float* osf = out + sB*9  + (size_t)b*36;
        float* opp = out + sB*45 + (size_t)b*36;
        #pragma unroll
        for (int s = 0; s < 12; ++s) {
            osf[s*3+0]=fx[s]; osf[s*3+1]=fy[s]; osf[s*3+2]=fz[s];
            opp[s*3+0]=px[s]; opp[s*3+1]=py[s]; opp[s*3+2]=pz[s];
        }
    }
}

extern "C" void kernel_launch(void* const* d_in, const int* in_sizes, int n_in,
                              void* d_out, int out_size, void* d_ws, size_t ws_size,
                              hipStream_t stream) {
    const float* joints = (const float*)d_in[0];
    const float* jori   = (const float*)d_in[1];
    float* out = (float*)d_out;
    const int B = in_sizes[0] / 72;   // joints is (B, 24, 3)
    const int block = 256;
    const int grid  = (B + block - 1) / block;
    contact_kernel<<<grid, block, 0, stream>>>(joints, jori, out, B);
}